// Round 4
// baseline (21014.864 us; speedup 1.0000x reference)
//
#include <hip/hip_runtime.h>

// RVAE on MI355X. Design notes (KERNEL-tier):
//  - 128 persistent WGs (one per batch row). Recurrent weights (768x256 f16)
//    are register-resident: 256 thr/WG, each thread owns 3 gate-rows
//    (r,z,n for one h-index) = 96 NAMED uint4 vars = 384 VGPRs.
//    NAMED variables, not arrays: R1/R2 showed uint32 wr[128] goes to
//    scratch (VGPR_Count=84, 19.6ms) regardless of __launch_bounds__ —
//    the 128-iter unrolled load loop defeats SROA. Macro-generated named
//    uint4s sidestep the alloca entirely.
//  - 256 thr = 4 waves = 1 wave/SIMD -> 512-VGPR budget (vs 170 at 768thr).
//  - 3 rows/thread fuses the GRU gate recombination in-thread: no s_rz LDS
//    round-trip; enc = 2 barriers/step, decA = 4, decB = 3.
//  - All matvecs via v_dot2_f32_f16 (f16 pairs, f32 accumulate); gates,
//    reductions, recon/kld in f32. absmax was 0.0078 vs 2.5e5 threshold.
//  - Encoder fuses xh -> Wz[:,H:2H] projection (8 floats/step) so
//    xh[L,B,256] (268MB) is never materialized.
//  - decA/decB split because Whh2+Whh3 = 768 VGPRs don't co-fit.

typedef unsigned int uint32;
typedef _Float16 half2v __attribute__((ext_vector_type(2)));

#define LOG2PI_F 1.8378770664093453f

__device__ __forceinline__ float dot2f(uint32 w, uint32 h, float acc) {
#if __has_builtin(__builtin_amdgcn_fdot2)
  return __builtin_amdgcn_fdot2(__builtin_bit_cast(half2v, w),
                                __builtin_bit_cast(half2v, h), acc, false);
#else
  half2v a = __builtin_bit_cast(half2v, w);
  half2v b = __builtin_bit_cast(half2v, h);
  return acc + (float)a.x * (float)b.x + (float)a.y * (float)b.y;
#endif
}

__device__ __forceinline__ uint32 packh2(float a, float b) {
  half2v v;
  v.x = (_Float16)a;
  v.y = (_Float16)b;
  return __builtin_bit_cast(uint32, v);
}

__device__ __forceinline__ float wredsum64(float v) {
  v += __shfl_xor(v, 32); v += __shfl_xor(v, 16); v += __shfl_xor(v, 8);
  v += __shfl_xor(v, 4);  v += __shfl_xor(v, 2);  v += __shfl_xor(v, 1);
  return v;
}

__device__ __forceinline__ float sigm(float x) { return 1.0f / (1.0f + expf(-x)); }
__device__ __forceinline__ float tanh_(float x) { return 1.0f - 2.0f / (expf(2.0f * x) + 1.0f); }

#define R32(M) M(0) M(1) M(2) M(3) M(4) M(5) M(6) M(7) M(8) M(9) M(10) M(11) \
  M(12) M(13) M(14) M(15) M(16) M(17) M(18) M(19) M(20) M(21) M(22) M(23) \
  M(24) M(25) M(26) M(27) M(28) M(29) M(30) M(31)

// Load 3 weight rows (r,z,n) as 96 named uint4s.
#define LDW(n) uint4 u##n = uq4[n]; uint4 v##n = vq4[n]; uint4 w##n = wq4[n];

// 12 dot2 per 4-pair chunk; hv is a same-address LDS broadcast (conflict-free).
#define HDOT(n) { uint4 hv = hq4[n]; \
  ar0 = dot2f(u##n.x, hv.x, ar0); ar1 = dot2f(u##n.y, hv.y, ar1); \
  ar0 = dot2f(u##n.z, hv.z, ar0); ar1 = dot2f(u##n.w, hv.w, ar1); \
  az0 = dot2f(v##n.x, hv.x, az0); az1 = dot2f(v##n.y, hv.y, az1); \
  az0 = dot2f(v##n.z, hv.z, az0); az1 = dot2f(v##n.w, hv.w, az1); \
  an0 = dot2f(w##n.x, hv.x, an0); an1 = dot2f(w##n.y, hv.y, an1); \
  an0 = dot2f(w##n.z, hv.z, an0); an1 = dot2f(w##n.w, hv.w, an1); }

// ---------------- prep: repack weights into ws ----------------
// wq1/2/3: [768 rows][128 pairs] uint32 = packh2(Whh[k][2i], Whh[k][2i+1])
//          (row-major so each thread loads its 3x32 uint4s contiguously)
// wih1t: [16][768] f16x2 pairs of Wih1; wih2t/wih3t: [2][768]
// wz1t/wz2t: [256][9] f32 (pad col 9 for bank spread)
// wxp: [128][64] f16x2 pairs over i of (Wxl;Wxs)
__global__ void prep_kernel(const float* __restrict__ Wih1, const float* __restrict__ Whh1,
                            const float* __restrict__ Wih2, const float* __restrict__ Whh2,
                            const float* __restrict__ Wih3, const float* __restrict__ Whh3,
                            const float* __restrict__ Wzl, const float* __restrict__ Wzs,
                            const float* __restrict__ Wxl, const float* __restrict__ Wxs,
                            uint32* wq1, uint32* wq2, uint32* wq3,
                            uint32* wih1t, uint32* wih2t, uint32* wih3t,
                            float* wz1t, float* wz2t, uint32* wxp) {
  int id = blockIdx.x * blockDim.x + threadIdx.x;
  int str = gridDim.x * blockDim.x;
  for (int n = id; n < 768 * 128; n += str) {
    int k = n >> 7, i = n & 127;
    wq1[n] = packh2(Whh1[k * 256 + 2 * i], Whh1[k * 256 + 2 * i + 1]);
    wq2[n] = packh2(Whh2[k * 256 + 2 * i], Whh2[k * 256 + 2 * i + 1]);
    wq3[n] = packh2(Whh3[k * 256 + 2 * i], Whh3[k * 256 + 2 * i + 1]);
  }
  for (int n = id; n < 16 * 768; n += str) {
    int i = n / 768, k = n % 768;
    wih1t[n] = packh2(Wih1[k * 32 + 2 * i], Wih1[k * 32 + 2 * i + 1]);
  }
  for (int n = id; n < 2 * 768; n += str) {
    int i = n / 768, k = n % 768;
    wih2t[n] = packh2(Wih2[k * 4 + 2 * i], Wih2[k * 4 + 2 * i + 1]);
    wih3t[n] = packh2(Wih3[k * 4 + 2 * i], Wih3[k * 4 + 2 * i + 1]);
  }
  for (int n = id; n < 256 * 8; n += str) {
    int i = n >> 3, o = n & 7;
    wz1t[i * 9 + o] = (o < 4) ? Wzl[o * 512 + i] : Wzs[(o - 4) * 512 + i];
    wz2t[i * 9 + o] = (o < 4) ? Wzl[o * 512 + 256 + i] : Wzs[(o - 4) * 512 + 256 + i];
  }
  for (int n = id; n < 128 * 64; n += str) {
    int i2 = n >> 6, o = n & 63;
    float a = (o < 32) ? Wxl[o * 256 + 2 * i2] : Wxs[(o - 32) * 256 + 2 * i2];
    float b = (o < 32) ? Wxl[o * 256 + 2 * i2 + 1] : Wxs[(o - 32) * 256 + 2 * i2 + 1];
    wxp[n] = packh2(a, b);
  }
}

// ---------------- encoder: reverse GRU + fused xh->Wz projection ----------------
__global__ __launch_bounds__(256, 1) void enc_kernel(
    const float* __restrict__ x, const float* __restrict__ bih1,
    const float* __restrict__ bhh1, const uint32* __restrict__ wq1,
    const uint32* __restrict__ wih1t, const float* __restrict__ wz2t,
    float* __restrict__ zx) {
  const int b = blockIdx.x, k = threadIdx.x;
  __shared__ uint32 wih[16 * 768];          // 48KB
  __shared__ float wz[256 * 9];             // 9KB
  __shared__ float h[256];
  __shared__ __align__(16) uint32 hpk[128];
  __shared__ uint32 xpk[16];

  const uint4* uq4 = (const uint4*)(wq1 + (size_t)k * 128);
  const uint4* vq4 = (const uint4*)(wq1 + (size_t)(k + 256) * 128);
  const uint4* wq4 = (const uint4*)(wq1 + (size_t)(k + 512) * 128);
  const uint4* hq4 = (const uint4*)hpk;
  R32(LDW)
  const float bir = bih1[k], biz = bih1[k + 256], bin = bih1[k + 512];
  const float bhr = bhh1[k], bhz = bhh1[k + 256], bhn = bhh1[k + 512];
  for (int i = k; i < 16 * 768; i += 256) wih[i] = wih1t[i];
  for (int i = k; i < 256 * 9; i += 256) wz[i] = wz2t[i];
  float h_reg = 0.0f;
  h[k] = 0.0f;
  if (k < 128) hpk[k] = 0u;
  const float* xb = x + (size_t)b * (2048 * 32);
  if (k < 16) xpk[k] = packh2(xb[2047 * 32 + 2 * k], xb[2047 * 32 + 2 * k + 1]);
  __syncthreads();

  for (int t = 2047; t >= 0; --t) {
    // ---- dots (reads xpk/hpk) + prefetch next x ----
    float xn0 = 0.f, xn1 = 0.f;
    if (k < 16 && t > 0) { xn0 = xb[(t - 1) * 32 + 2 * k]; xn1 = xb[(t - 1) * 32 + 2 * k + 1]; }
    float air = bir, aiz = biz, ain = bin;
#pragma unroll
    for (int i = 0; i < 16; ++i) {
      uint32 xv = xpk[i];
      air = dot2f(wih[i * 768 + k], xv, air);
      aiz = dot2f(wih[i * 768 + 256 + k], xv, aiz);
      ain = dot2f(wih[i * 768 + 512 + k], xv, ain);
    }
    float ar0 = 0.f, ar1 = 0.f, az0 = 0.f, az1 = 0.f, an0 = 0.f, an1 = 0.f;
    R32(HDOT)
    __syncthreads();  // B1: all hpk/xpk reads done
    // ---- gates (in-thread recombination) + state update + staging ----
    float r = sigm(air + bhr + ar0 + ar1);
    float zg = sigm(aiz + bhz + az0 + az1);
    float n = tanh_(ain + r * (bhn + an0 + an1));
    float hn = (1.0f - zg) * n + zg * h_reg;
    h_reg = hn;
    h[k] = hn;
    float ho = __shfl_xor(hn, 1);
    if (!(k & 1)) hpk[k >> 1] = packh2(hn, ho);
    if (k < 16 && t > 0) xpk[k] = packh2(xn0, xn1);
    __syncthreads();  // B2: new h/hpk visible
    // ---- fused projection: wave wv computes outputs 2wv, 2wv+1 ----
    {
      int wv = k >> 6, l = k & 63, o0 = 2 * wv, o1 = o0 + 1;
      float s0 = 0.f, s1 = 0.f;
#pragma unroll
      for (int m = 0; m < 4; ++m) {
        float hv = h[l + 64 * m];
        const float* wr_ = &wz[(l + 64 * m) * 9];
        s0 += hv * wr_[o0];
        s1 += hv * wr_[o1];
      }
      s0 = wredsum64(s0);
      s1 = wredsum64(s1);
      if (l == 0) {
        size_t tb8 = ((size_t)t * 128 + b) * 8;
        zx[tb8 + o0] = s0;
        zx[tb8 + o1] = s1;
      }
    }
    // no loop-end barrier: next h write is after B1(t+1)
  }
}

// ---------------- decoder stage A: phi GRU + z sample + kld ----------------
__global__ __launch_bounds__(256, 1) void decA_kernel(
    const float* __restrict__ eps, const float* __restrict__ bih2,
    const float* __restrict__ bhh2, const uint32* __restrict__ wq2,
    const uint32* __restrict__ wih2t, const float* __restrict__ wz1t,
    const float* __restrict__ bzl, const float* __restrict__ bzs,
    const float* __restrict__ zx, uint32* __restrict__ zbuf,
    float* __restrict__ kld_out) {
  const int b = blockIdx.x, k = threadIdx.x;
  __shared__ uint32 wih[2 * 768];
  __shared__ float wz[256 * 9];
  __shared__ float h[256];
  __shared__ __align__(16) uint32 hpk[128];
  __shared__ float zl[8];
  __shared__ uint32 zpk[2];

  const uint4* uq4 = (const uint4*)(wq2 + (size_t)k * 128);
  const uint4* vq4 = (const uint4*)(wq2 + (size_t)(k + 256) * 128);
  const uint4* wq4 = (const uint4*)(wq2 + (size_t)(k + 512) * 128);
  const uint4* hq4 = (const uint4*)hpk;
  R32(LDW)
  const float bir = bih2[k], biz = bih2[k + 256], bin = bih2[k + 512];
  const float bhr = bhh2[k], bhz = bhh2[k + 256], bhn = bhh2[k + 512];
  float bzlr = 0.f, bzsr = 0.f;
  if (k < 4) { bzlr = bzl[k]; bzsr = bzs[k]; }
  for (int i = k; i < 2 * 768; i += 256) wih[i] = wih2t[i];
  for (int i = k; i < 256 * 9; i += 256) wz[i] = wz1t[i];
  float h_reg = 0.0f, kacc = 0.0f;
  h[k] = 0.0f;
  if (k < 128) hpk[k] = 0u;
  if (k < 2) zpk[k] = 0u;
  __syncthreads();

  for (int t = 0; t < 2048; ++t) {
    const size_t tb = (size_t)t * 128 + b;
    // ---- prefetch (hidden under dots) ----
    float ev = 0.f, zxa = 0.f, zxb = 0.f;
    if (k < 4) { ev = eps[tb * 4 + k]; zxa = zx[tb * 8 + k]; zxb = zx[tb * 8 + k + 4]; }
    // ---- dots ----
    uint32 zi0 = zpk[0], zi1 = zpk[1];
    float air = dot2f(wih[k], zi0, bir);       air = dot2f(wih[768 + k], zi1, air);
    float aiz = dot2f(wih[256 + k], zi0, biz); aiz = dot2f(wih[768 + 256 + k], zi1, aiz);
    float ain = dot2f(wih[512 + k], zi0, bin); ain = dot2f(wih[768 + 512 + k], zi1, ain);
    float ar0 = 0.f, ar1 = 0.f, az0 = 0.f, az1 = 0.f, an0 = 0.f, an1 = 0.f;
    R32(HDOT)
    __syncthreads();  // B1
    float r = sigm(air + bhr + ar0 + ar1);
    float zg = sigm(aiz + bhz + az0 + az1);
    float n = tanh_(ain + r * (bhn + an0 + an1));
    float hn = (1.0f - zg) * n + zg * h_reg;
    h_reg = hn;
    h[k] = hn;
    float ho = __shfl_xor(hn, 1);
    if (!(k & 1)) hpk[k >> 1] = packh2(hn, ho);
    __syncthreads();  // B2
    // ---- z projection (4 waves x 2 outputs) ----
    {
      int wv = k >> 6, l = k & 63, o0 = 2 * wv, o1 = o0 + 1;
      float s0 = 0.f, s1 = 0.f;
#pragma unroll
      for (int m = 0; m < 4; ++m) {
        float hv = h[l + 64 * m];
        const float* wr_ = &wz[(l + 64 * m) * 9];
        s0 += hv * wr_[o0];
        s1 += hv * wr_[o1];
      }
      s0 = wredsum64(s0);
      s1 = wredsum64(s1);
      if (l == 0) { zl[o0] = s0; zl[o1] = s1; }
    }
    __syncthreads();  // B3: zl ready
    // ---- rsample + kld (threads 0..3) ----
    if (k < 4) {
      float loc = zl[k] + bzlr + zxa;
      float lv = zl[k + 4] + bzsr + zxb;
      float sc = expf(0.5f * lv);
      float zv = loc + sc * ev;
      kacc += 0.5f * (sc * sc + loc * loc - 1.0f - lv);
      float zo = __shfl_xor(zv, 1);
      if (!(k & 1)) {
        uint32 pk = packh2(zv, zo);
        zpk[k >> 1] = pk;
        zbuf[tb * 2 + (k >> 1)] = pk;
      }
    }
    __syncthreads();  // B4: zpk ready for next dots
  }
  if (k < 4) atomicAdd(kld_out, kacc);
}

// ---------------- decoder stage B: theta GRU + x linears + recon ----------------
__global__ __launch_bounds__(256, 1) void decB_kernel(
    const float* __restrict__ x, const float* __restrict__ bih3,
    const float* __restrict__ bhh3, const uint32* __restrict__ wq3,
    const uint32* __restrict__ wih3t, const uint32* __restrict__ wxp_g,
    const float* __restrict__ bxl, const float* __restrict__ bxs,
    const uint32* __restrict__ zbuf, float* __restrict__ y,
    float* __restrict__ recon_out) {
  const int b = blockIdx.x, k = threadIdx.x;
  __shared__ uint32 wih[2 * 768];
  __shared__ uint32 wxpL[128 * 65];          // padded: bank-spread for strided reads
  __shared__ __align__(16) uint32 hpk[128];
  __shared__ float xl[64];
  __shared__ uint32 zpk[2];

  const uint4* uq4 = (const uint4*)(wq3 + (size_t)k * 128);
  const uint4* vq4 = (const uint4*)(wq3 + (size_t)(k + 256) * 128);
  const uint4* wq4 = (const uint4*)(wq3 + (size_t)(k + 512) * 128);
  const uint4* hq4 = (const uint4*)hpk;
  R32(LDW)
  const float bir = bih3[k], biz = bih3[k + 256], bin = bih3[k + 512];
  const float bhr = bhh3[k], bhz = bhh3[k + 256], bhn = bhh3[k + 512];
  const int oo = k >> 2, qq = k & 3;
  float bx_r = 0.f;
  if (qq == 0) bx_r = (oo < 32) ? bxl[oo] : bxs[oo - 32];
  for (int i = k; i < 128 * 64; i += 256) wxpL[(i >> 6) * 65 + (i & 63)] = wxp_g[i];
  for (int i = k; i < 2 * 768; i += 256) wih[i] = wih3t[i];
  float h_reg = 0.0f, racc = 0.0f;
  if (k < 128) hpk[k] = 0u;
  if (k < 2) zpk[k] = zbuf[(size_t)b * 2 + k];  // t = 0
  const float* xb = x + (size_t)b * (2048 * 32);
  float* yb = y + (size_t)b * (2048 * 32);
  __syncthreads();

  for (int t = 0; t < 2048; ++t) {
    // ---- prefetch ----
    float xv = 0.f;
    uint32 zn = 0u;
    if (k < 32) xv = xb[t * 32 + k];
    if (k < 2 && t + 1 < 2048) zn = zbuf[((size_t)(t + 1) * 128 + b) * 2 + k];
    // ---- dots ----
    uint32 zi0 = zpk[0], zi1 = zpk[1];
    float air = dot2f(wih[k], zi0, bir);       air = dot2f(wih[768 + k], zi1, air);
    float aiz = dot2f(wih[256 + k], zi0, biz); aiz = dot2f(wih[768 + 256 + k], zi1, aiz);
    float ain = dot2f(wih[512 + k], zi0, bin); ain = dot2f(wih[768 + 512 + k], zi1, ain);
    float ar0 = 0.f, ar1 = 0.f, az0 = 0.f, az1 = 0.f, an0 = 0.f, an1 = 0.f;
    R32(HDOT)
    __syncthreads();  // B1
    float r = sigm(air + bhr + ar0 + ar1);
    float zg = sigm(aiz + bhz + az0 + az1);
    float n = tanh_(ain + r * (bhn + an0 + an1));
    float hn = (1.0f - zg) * n + zg * h_reg;
    h_reg = hn;
    float ho = __shfl_xor(hn, 1);
    if (!(k & 1)) hpk[k >> 1] = packh2(hn, ho);
    if (k < 2 && t + 1 < 2048) zpk[k] = zn;
    __syncthreads();  // B2
    // ---- x-linear: quad (o,q), each sums 32 interleaved pairs ----
    {
      float s = 0.f;
#pragma unroll
      for (int m = 0; m < 32; ++m) {
        int i2 = qq + 4 * m;
        s = dot2f(wxpL[i2 * 65 + oo], hpk[i2], s);
      }
      s += __shfl_xor(s, 2);
      s += __shfl_xor(s, 1);
      if (qq == 0) xl[oo] = s + bx_r;
    }
    __syncthreads();  // B3: xl ready
    // ---- recon + y write (threads 0..31) ----
    if (k < 32) {
      float loc = xl[k], lv = xl[k + 32];
      yb[t * 32 + k] = loc;
      float d = xv - loc;
      racc += 0.5f * d * d * expf(-lv) + 0.5f * lv + 0.5f * LOG2PI_F;
    }
    // no loop-end barrier: next writes to hpk/zpk are after B1(t+1),
    // next xl write is after B2(t+1)
  }
  if (k < 32) {
    racc += __shfl_xor(racc, 16); racc += __shfl_xor(racc, 8);
    racc += __shfl_xor(racc, 4);  racc += __shfl_xor(racc, 2);
    racc += __shfl_xor(racc, 1);
    if (k == 0) atomicAdd(recon_out, racc);
  }
}

// ---------------- launcher ----------------
extern "C" void kernel_launch(void* const* d_in, const int* in_sizes, int n_in,
                              void* d_out, int out_size, void* d_ws, size_t ws_size,
                              hipStream_t stream) {
  const float* x    = (const float*)d_in[0];
  const float* eps  = (const float*)d_in[1];
  const float* Wih1 = (const float*)d_in[2];
  const float* Whh1 = (const float*)d_in[3];
  const float* bih1 = (const float*)d_in[4];
  const float* bhh1 = (const float*)d_in[5];
  const float* Wih2 = (const float*)d_in[6];
  const float* Whh2 = (const float*)d_in[7];
  const float* bih2 = (const float*)d_in[8];
  const float* bhh2 = (const float*)d_in[9];
  const float* Wih3 = (const float*)d_in[10];
  const float* Whh3 = (const float*)d_in[11];
  const float* bih3 = (const float*)d_in[12];
  const float* bhh3 = (const float*)d_in[13];
  const float* Wzl  = (const float*)d_in[14];
  const float* bzl  = (const float*)d_in[15];
  const float* Wzs  = (const float*)d_in[16];
  const float* bzs  = (const float*)d_in[17];
  const float* Wxl  = (const float*)d_in[18];
  const float* bxl  = (const float*)d_in[19];
  const float* Wxs  = (const float*)d_in[20];
  const float* bxs  = (const float*)d_in[21];

  float* ws = (float*)d_ws;
  uint32* wq1   = (uint32*)(ws + 0);        // 98304
  uint32* wq2   = (uint32*)(ws + 98304);    // 98304
  uint32* wq3   = (uint32*)(ws + 196608);   // 98304
  uint32* wih1t = (uint32*)(ws + 294912);   // 12288
  uint32* wih2t = (uint32*)(ws + 307200);   // 1536
  uint32* wih3t = (uint32*)(ws + 308736);   // 1536
  float*  wz1t  = ws + 310272;              // 2304
  float*  wz2t  = ws + 312576;              // 2304
  uint32* wxp   = (uint32*)(ws + 314880);   // 8192
  float*  zx    = ws + 323072;              // 2097152  [L][B][8]
  uint32* zbuf  = (uint32*)(ws + 2420224);  // 524288   [L][B] f16x2 pairs

  float* out = (float*)d_out;  // [B*L*F] y_loc, then recon, kld
  hipMemsetAsync(out + 8388608, 0, 8, stream);

  prep_kernel<<<128, 256, 0, stream>>>(Wih1, Whh1, Wih2, Whh2, Wih3, Whh3,
                                       Wzl, Wzs, Wxl, Wxs,
                                       wq1, wq2, wq3, wih1t, wih2t, wih3t,
                                       wz1t, wz2t, wxp);
  enc_kernel<<<128, 256, 0, stream>>>(x, bih1, bhh1, wq1, wih1t, wz2t, zx);
  decA_kernel<<<128, 256, 0, stream>>>(eps, bih2, bhh2, wq2, wih2t, wz1t,
                                       bzl, bzs, zx, zbuf, out + 8388609);
  decB_kernel<<<128, 256, 0, stream>>>(x, bih3, bhh3, wq3, wih3t, wxp,
                                       bxl, bxs, zbuf, out, out + 8388608);
}

// Round 5
// 20765.395 us; speedup vs baseline: 1.0120x; 1.0120x over previous
//
#include <hip/hip_runtime.h>

// RVAE on MI355X. Design notes (KERNEL-tier):
//  - 128 persistent WGs (one per batch row). Recurrent weights (768x256 f16)
//    register-resident: 256 thr/WG, each thread owns 3 gate-rows = 96 NAMED
//    uint4 vars = 384 regs (unified VGPR+AGPR file holds 512/wave at 1 wave/EU).
//  - amdgpu_waves_per_eu(1,1) is LOAD-BEARING: R4 showed __launch_bounds__(256,1)
//    alone leaves the scheduler targeting >1 wave/EU, so it spilled ~160 weight
//    regs to scratch (VGPR_Count=220, decA FETCH 65MB vs 13MB inputs, 21ms).
//    Pinning max waves/EU = 1 makes RP reduction below 512 worthless.
//  - NAMED vars, not arrays: R1/R2 showed uint32 wr[128] becomes an alloca in
//    scratch (VGPR_Count=84) — unrolled-array loads defeat SROA.
//  - All matvecs via v_dot2_f32_f16 (f16 pairs, f32 accumulate); gates,
//    reductions, recon/kld in f32. absmax 0.0078 vs 2.5e5 threshold.
//  - Encoder fuses xh -> Wz[:,H:2H] projection (8 floats/step) so
//    xh[L,B,256] (268MB) is never materialized.
//  - decA: wave wv computes loc[wv] & logvar[wv]; lane0 samples z locally ->
//    no zl[] LDS round-trip, 3 barriers/step (was 4).
//  - decA/decB split because Whh2+Whh3 = 768 regs don't co-fit.

typedef unsigned int uint32;
typedef unsigned short uint16;
typedef _Float16 half2v __attribute__((ext_vector_type(2)));

#define LOG2PI_F 1.8378770664093453f

__device__ __forceinline__ float dot2f(uint32 w, uint32 h, float acc) {
#if __has_builtin(__builtin_amdgcn_fdot2)
  return __builtin_amdgcn_fdot2(__builtin_bit_cast(half2v, w),
                                __builtin_bit_cast(half2v, h), acc, false);
#else
  half2v a = __builtin_bit_cast(half2v, w);
  half2v b = __builtin_bit_cast(half2v, h);
  return acc + (float)a.x * (float)b.x + (float)a.y * (float)b.y;
#endif
}

__device__ __forceinline__ uint32 packh2(float a, float b) {
  half2v v;
  v.x = (_Float16)a;
  v.y = (_Float16)b;
  return __builtin_bit_cast(uint32, v);
}

__device__ __forceinline__ float wredsum64(float v) {
  v += __shfl_xor(v, 32); v += __shfl_xor(v, 16); v += __shfl_xor(v, 8);
  v += __shfl_xor(v, 4);  v += __shfl_xor(v, 2);  v += __shfl_xor(v, 1);
  return v;
}

__device__ __forceinline__ float sigm(float x) { return 1.0f / (1.0f + expf(-x)); }
__device__ __forceinline__ float tanh_(float x) { return 1.0f - 2.0f / (expf(2.0f * x) + 1.0f); }

#define R32(M) M(0) M(1) M(2) M(3) M(4) M(5) M(6) M(7) M(8) M(9) M(10) M(11) \
  M(12) M(13) M(14) M(15) M(16) M(17) M(18) M(19) M(20) M(21) M(22) M(23) \
  M(24) M(25) M(26) M(27) M(28) M(29) M(30) M(31)

// Load 3 weight rows (r,z,n) as 96 named uint4s.
#define LDW(n) uint4 u##n = uq4[n]; uint4 v##n = vq4[n]; uint4 w##n = wq4[n];

// 12 dot2 per 4-pair chunk; hv is a same-address LDS broadcast (conflict-free).
#define HDOT(n) { uint4 hv = hq4[n]; \
  ar0 = dot2f(u##n.x, hv.x, ar0); ar1 = dot2f(u##n.y, hv.y, ar1); \
  ar0 = dot2f(u##n.z, hv.z, ar0); ar1 = dot2f(u##n.w, hv.w, ar1); \
  az0 = dot2f(v##n.x, hv.x, az0); az1 = dot2f(v##n.y, hv.y, az1); \
  az0 = dot2f(v##n.z, hv.z, az0); az1 = dot2f(v##n.w, hv.w, az1); \
  an0 = dot2f(w##n.x, hv.x, an0); an1 = dot2f(w##n.y, hv.y, an1); \
  an0 = dot2f(w##n.z, hv.z, an0); an1 = dot2f(w##n.w, hv.w, an1); }

#define KPIN __launch_bounds__(256) __attribute__((amdgpu_waves_per_eu(1, 1)))

// ---------------- prep: repack weights into ws ----------------
__global__ void prep_kernel(const float* __restrict__ Wih1, const float* __restrict__ Whh1,
                            const float* __restrict__ Wih2, const float* __restrict__ Whh2,
                            const float* __restrict__ Wih3, const float* __restrict__ Whh3,
                            const float* __restrict__ Wzl, const float* __restrict__ Wzs,
                            const float* __restrict__ Wxl, const float* __restrict__ Wxs,
                            uint32* wq1, uint32* wq2, uint32* wq3,
                            uint32* wih1t, uint32* wih2t, uint32* wih3t,
                            float* wz1t, float* wz2t, uint32* wxp) {
  int id = blockIdx.x * blockDim.x + threadIdx.x;
  int str = gridDim.x * blockDim.x;
  for (int n = id; n < 768 * 128; n += str) {
    int k = n >> 7, i = n & 127;
    wq1[n] = packh2(Whh1[k * 256 + 2 * i], Whh1[k * 256 + 2 * i + 1]);
    wq2[n] = packh2(Whh2[k * 256 + 2 * i], Whh2[k * 256 + 2 * i + 1]);
    wq3[n] = packh2(Whh3[k * 256 + 2 * i], Whh3[k * 256 + 2 * i + 1]);
  }
  for (int n = id; n < 16 * 768; n += str) {
    int i = n / 768, k = n % 768;
    wih1t[n] = packh2(Wih1[k * 32 + 2 * i], Wih1[k * 32 + 2 * i + 1]);
  }
  for (int n = id; n < 2 * 768; n += str) {
    int i = n / 768, k = n % 768;
    wih2t[n] = packh2(Wih2[k * 4 + 2 * i], Wih2[k * 4 + 2 * i + 1]);
    wih3t[n] = packh2(Wih3[k * 4 + 2 * i], Wih3[k * 4 + 2 * i + 1]);
  }
  for (int n = id; n < 256 * 8; n += str) {
    int i = n >> 3, o = n & 7;
    wz1t[i * 9 + o] = (o < 4) ? Wzl[o * 512 + i] : Wzs[(o - 4) * 512 + i];
    wz2t[i * 9 + o] = (o < 4) ? Wzl[o * 512 + 256 + i] : Wzs[(o - 4) * 512 + 256 + i];
  }
  for (int n = id; n < 128 * 64; n += str) {
    int i2 = n >> 6, o = n & 63;
    float a = (o < 32) ? Wxl[o * 256 + 2 * i2] : Wxs[(o - 32) * 256 + 2 * i2];
    float b = (o < 32) ? Wxl[o * 256 + 2 * i2 + 1] : Wxs[(o - 32) * 256 + 2 * i2 + 1];
    wxp[n] = packh2(a, b);
  }
}

// ---------------- encoder: reverse GRU + fused xh->Wz projection ----------------
__global__ KPIN void enc_kernel(
    const float* __restrict__ x, const float* __restrict__ bih1,
    const float* __restrict__ bhh1, const uint32* __restrict__ wq1,
    const uint32* __restrict__ wih1t, const float* __restrict__ wz2t,
    float* __restrict__ zx) {
  const int b = blockIdx.x, k = threadIdx.x;
  __shared__ uint32 wih[16 * 768];          // 48KB
  __shared__ float wz[256 * 9];             // 9KB
  __shared__ float h[256];
  __shared__ __align__(16) uint32 hpk[128];
  __shared__ uint32 xpk[16];

  const uint4* uq4 = (const uint4*)(wq1 + (size_t)k * 128);
  const uint4* vq4 = (const uint4*)(wq1 + (size_t)(k + 256) * 128);
  const uint4* wq4 = (const uint4*)(wq1 + (size_t)(k + 512) * 128);
  const uint4* hq4 = (const uint4*)hpk;
  R32(LDW)
  const float bir = bih1[k], biz = bih1[k + 256], bin = bih1[k + 512];
  const float bhr = bhh1[k], bhz = bhh1[k + 256], bhn = bhh1[k + 512];
  for (int i = k; i < 16 * 768; i += 256) wih[i] = wih1t[i];
  for (int i = k; i < 256 * 9; i += 256) wz[i] = wz2t[i];
  float h_reg = 0.0f;
  h[k] = 0.0f;
  if (k < 128) hpk[k] = 0u;
  const float* xb = x + (size_t)b * (2048 * 32);
  if (k < 16) xpk[k] = packh2(xb[2047 * 32 + 2 * k], xb[2047 * 32 + 2 * k + 1]);
  __syncthreads();

  for (int t = 2047; t >= 0; --t) {
    // ---- dots (reads xpk/hpk) + prefetch next x ----
    float xn0 = 0.f, xn1 = 0.f;
    if (k < 16 && t > 0) { xn0 = xb[(t - 1) * 32 + 2 * k]; xn1 = xb[(t - 1) * 32 + 2 * k + 1]; }
    float air = bir, aiz = biz, ain = bin;
#pragma unroll
    for (int i = 0; i < 16; ++i) {
      uint32 xv = xpk[i];
      air = dot2f(wih[i * 768 + k], xv, air);
      aiz = dot2f(wih[i * 768 + 256 + k], xv, aiz);
      ain = dot2f(wih[i * 768 + 512 + k], xv, ain);
    }
    float ar0 = 0.f, ar1 = 0.f, az0 = 0.f, az1 = 0.f, an0 = 0.f, an1 = 0.f;
    R32(HDOT)
    __syncthreads();  // B1: all hpk/xpk reads done
    // ---- gates (in-thread recombination) + state update + staging ----
    float r = sigm(air + bhr + ar0 + ar1);
    float zg = sigm(aiz + bhz + az0 + az1);
    float n = tanh_(ain + r * (bhn + an0 + an1));
    float hn = (1.0f - zg) * n + zg * h_reg;
    h_reg = hn;
    h[k] = hn;
    float ho = __shfl_xor(hn, 1);
    if (!(k & 1)) hpk[k >> 1] = packh2(hn, ho);
    if (k < 16 && t > 0) xpk[k] = packh2(xn0, xn1);
    __syncthreads();  // B2: new h/hpk visible
    // ---- fused projection: wave wv computes outputs 2wv, 2wv+1 ----
    {
      int wv = k >> 6, l = k & 63, o0 = 2 * wv, o1 = o0 + 1;
      float s0 = 0.f, s1 = 0.f;
#pragma unroll
      for (int m = 0; m < 4; ++m) {
        float hv = h[l + 64 * m];
        const float* wr_ = &wz[(l + 64 * m) * 9];
        s0 += hv * wr_[o0];
        s1 += hv * wr_[o1];
      }
      s0 = wredsum64(s0);
      s1 = wredsum64(s1);
      if (l == 0) {
        size_t tb8 = ((size_t)t * 128 + b) * 8;
        zx[tb8 + o0] = s0;
        zx[tb8 + o1] = s1;
      }
    }
    // no loop-end barrier: next h write is after B1(t+1)
  }
}

// ---------------- decoder stage A: phi GRU + z sample + kld ----------------
__global__ KPIN void decA_kernel(
    const float* __restrict__ eps, const float* __restrict__ bih2,
    const float* __restrict__ bhh2, const uint32* __restrict__ wq2,
    const uint32* __restrict__ wih2t, const float* __restrict__ wz1t,
    const float* __restrict__ bzl, const float* __restrict__ bzs,
    const float* __restrict__ zx, uint16* __restrict__ zbuf16,
    float* __restrict__ kld_out) {
  const int b = blockIdx.x, k = threadIdx.x;
  const int wv = k >> 6, l = k & 63;
  __shared__ uint32 wih[2 * 768];
  __shared__ float wz[256 * 9];
  __shared__ float h[256];
  __shared__ __align__(16) uint32 hpk[128];
  __shared__ __align__(8) uint16 zpk16[4];

  const uint4* uq4 = (const uint4*)(wq2 + (size_t)k * 128);
  const uint4* vq4 = (const uint4*)(wq2 + (size_t)(k + 256) * 128);
  const uint4* wq4 = (const uint4*)(wq2 + (size_t)(k + 512) * 128);
  const uint4* hq4 = (const uint4*)hpk;
  R32(LDW)
  const float bir = bih2[k], biz = bih2[k + 256], bin = bih2[k + 512];
  const float bhr = bhh2[k], bhz = bhh2[k + 256], bhn = bhh2[k + 512];
  const float bzlr = bzl[wv], bzsr = bzs[wv];
  for (int i = k; i < 2 * 768; i += 256) wih[i] = wih2t[i];
  for (int i = k; i < 256 * 9; i += 256) wz[i] = wz1t[i];
  float h_reg = 0.0f, kacc = 0.0f;
  h[k] = 0.0f;
  if (k < 128) hpk[k] = 0u;
  if (k < 4) zpk16[k] = (uint16)0;
  __syncthreads();

  for (int t = 0; t < 2048; ++t) {
    const size_t tb = (size_t)t * 128 + b;
    // ---- prefetch (lane0 of each wave; hidden under dots) ----
    float ev = 0.f, zxa = 0.f, zxb = 0.f;
    if (l == 0) { ev = eps[tb * 4 + wv]; zxa = zx[tb * 8 + wv]; zxb = zx[tb * 8 + wv + 4]; }
    // ---- dots ----
    uint32 zi0 = ((const uint32*)zpk16)[0], zi1 = ((const uint32*)zpk16)[1];
    float air = dot2f(wih[k], zi0, bir);       air = dot2f(wih[768 + k], zi1, air);
    float aiz = dot2f(wih[256 + k], zi0, biz); aiz = dot2f(wih[768 + 256 + k], zi1, aiz);
    float ain = dot2f(wih[512 + k], zi0, bin); ain = dot2f(wih[768 + 512 + k], zi1, ain);
    float ar0 = 0.f, ar1 = 0.f, az0 = 0.f, az1 = 0.f, an0 = 0.f, an1 = 0.f;
    R32(HDOT)
    __syncthreads();  // B1
    float r = sigm(air + bhr + ar0 + ar1);
    float zg = sigm(aiz + bhz + az0 + az1);
    float n = tanh_(ain + r * (bhn + an0 + an1));
    float hn = (1.0f - zg) * n + zg * h_reg;
    h_reg = hn;
    h[k] = hn;
    float ho = __shfl_xor(hn, 1);
    if (!(k & 1)) hpk[k >> 1] = packh2(hn, ho);
    __syncthreads();  // B2
    // ---- z proj: wave wv -> loc[wv], logvar[wv]; lane0 samples locally ----
    {
      float s0 = 0.f, s1 = 0.f;
#pragma unroll
      for (int m = 0; m < 4; ++m) {
        float hv = h[l + 64 * m];
        const float* wr_ = &wz[(l + 64 * m) * 9];
        s0 += hv * wr_[wv];
        s1 += hv * wr_[wv + 4];
      }
      s0 = wredsum64(s0);
      s1 = wredsum64(s1);
      if (l == 0) {
        float loc = s0 + bzlr + zxa;
        float lv = s1 + bzsr + zxb;
        float sc = expf(0.5f * lv);
        float zv = loc + sc * ev;
        kacc += 0.5f * (sc * sc + loc * loc - 1.0f - lv);
        uint16 hz = __builtin_bit_cast(uint16, (_Float16)zv);
        zpk16[wv] = hz;
        zbuf16[tb * 4 + wv] = hz;
      }
    }
    __syncthreads();  // B3: zpk16 ready for next dots
  }
  if (l == 0) atomicAdd(kld_out, kacc);
}

// ---------------- decoder stage B: theta GRU + x linears + recon ----------------
__global__ KPIN void decB_kernel(
    const float* __restrict__ x, const float* __restrict__ bih3,
    const float* __restrict__ bhh3, const uint32* __restrict__ wq3,
    const uint32* __restrict__ wih3t, const uint32* __restrict__ wxp_g,
    const float* __restrict__ bxl, const float* __restrict__ bxs,
    const uint32* __restrict__ zbuf, float* __restrict__ y,
    float* __restrict__ recon_out) {
  const int b = blockIdx.x, k = threadIdx.x;
  __shared__ uint32 wih[2 * 768];
  __shared__ uint32 wxpL[128 * 65];          // padded: bank-spread for strided reads
  __shared__ __align__(16) uint32 hpk[128];
  __shared__ float xl[64];
  __shared__ uint32 zpk[2];

  const uint4* uq4 = (const uint4*)(wq3 + (size_t)k * 128);
  const uint4* vq4 = (const uint4*)(wq3 + (size_t)(k + 256) * 128);
  const uint4* wq4 = (const uint4*)(wq3 + (size_t)(k + 512) * 128);
  const uint4* hq4 = (const uint4*)hpk;
  R32(LDW)
  const float bir = bih3[k], biz = bih3[k + 256], bin = bih3[k + 512];
  const float bhr = bhh3[k], bhz = bhh3[k + 256], bhn = bhh3[k + 512];
  const int oo = k >> 2, qq = k & 3;
  float bx_r = 0.f;
  if (qq == 0) bx_r = (oo < 32) ? bxl[oo] : bxs[oo - 32];
  for (int i = k; i < 128 * 64; i += 256) wxpL[(i >> 6) * 65 + (i & 63)] = wxp_g[i];
  for (int i = k; i < 2 * 768; i += 256) wih[i] = wih3t[i];
  float h_reg = 0.0f, racc = 0.0f;
  if (k < 128) hpk[k] = 0u;
  if (k < 2) zpk[k] = zbuf[(size_t)b * 2 + k];  // t = 0
  const float* xb = x + (size_t)b * (2048 * 32);
  float* yb = y + (size_t)b * (2048 * 32);
  __syncthreads();

  for (int t = 0; t < 2048; ++t) {
    // ---- prefetch ----
    float xv = 0.f;
    uint32 zn = 0u;
    if (k < 32) xv = xb[t * 32 + k];
    if (k < 2 && t + 1 < 2048) zn = zbuf[((size_t)(t + 1) * 128 + b) * 2 + k];
    // ---- dots ----
    uint32 zi0 = zpk[0], zi1 = zpk[1];
    float air = dot2f(wih[k], zi0, bir);       air = dot2f(wih[768 + k], zi1, air);
    float aiz = dot2f(wih[256 + k], zi0, biz); aiz = dot2f(wih[768 + 256 + k], zi1, aiz);
    float ain = dot2f(wih[512 + k], zi0, bin); ain = dot2f(wih[768 + 512 + k], zi1, ain);
    float ar0 = 0.f, ar1 = 0.f, az0 = 0.f, az1 = 0.f, an0 = 0.f, an1 = 0.f;
    R32(HDOT)
    __syncthreads();  // B1
    float r = sigm(air + bhr + ar0 + ar1);
    float zg = sigm(aiz + bhz + az0 + az1);
    float n = tanh_(ain + r * (bhn + an0 + an1));
    float hn = (1.0f - zg) * n + zg * h_reg;
    h_reg = hn;
    float ho = __shfl_xor(hn, 1);
    if (!(k & 1)) hpk[k >> 1] = packh2(hn, ho);
    if (k < 2 && t + 1 < 2048) zpk[k] = zn;
    __syncthreads();  // B2
    // ---- x-linear: quad (o,q), each sums 32 interleaved pairs ----
    {
      float s = 0.f;
#pragma unroll
      for (int m = 0; m < 32; ++m) {
        int i2 = qq + 4 * m;
        s = dot2f(wxpL[i2 * 65 + oo], hpk[i2], s);
      }
      s += __shfl_xor(s, 2);
      s += __shfl_xor(s, 1);
      if (qq == 0) xl[oo] = s + bx_r;
    }
    __syncthreads();  // B3: xl ready
    // ---- recon + y write (threads 0..31) ----
    if (k < 32) {
      float loc = xl[k], lv = xl[k + 32];
      yb[t * 32 + k] = loc;
      float d = xv - loc;
      racc += 0.5f * d * d * expf(-lv) + 0.5f * lv + 0.5f * LOG2PI_F;
    }
    // no loop-end barrier: next writes to hpk/zpk are after B1(t+1),
    // next xl write is after B2(t+1)
  }
  if (k < 32) {
    racc += __shfl_xor(racc, 16); racc += __shfl_xor(racc, 8);
    racc += __shfl_xor(racc, 4);  racc += __shfl_xor(racc, 2);
    racc += __shfl_xor(racc, 1);
    if (k == 0) atomicAdd(recon_out, racc);
  }
}

// ---------------- launcher ----------------
extern "C" void kernel_launch(void* const* d_in, const int* in_sizes, int n_in,
                              void* d_out, int out_size, void* d_ws, size_t ws_size,
                              hipStream_t stream) {
  const float* x    = (const float*)d_in[0];
  const float* eps  = (const float*)d_in[1];
  const float* Wih1 = (const float*)d_in[2];
  const float* Whh1 = (const float*)d_in[3];
  const float* bih1 = (const float*)d_in[4];
  const float* bhh1 = (const float*)d_in[5];
  const float* Wih2 = (const float*)d_in[6];
  const float* Whh2 = (const float*)d_in[7];
  const float* bih2 = (const float*)d_in[8];
  const float* bhh2 = (const float*)d_in[9];
  const float* Wih3 = (const float*)d_in[10];
  const float* Whh3 = (const float*)d_in[11];
  const float* bih3 = (const float*)d_in[12];
  const float* bhh3 = (const float*)d_in[13];
  const float* Wzl  = (const float*)d_in[14];
  const float* bzl  = (const float*)d_in[15];
  const float* Wzs  = (const float*)d_in[16];
  const float* bzs  = (const float*)d_in[17];
  const float* Wxl  = (const float*)d_in[18];
  const float* bxl  = (const float*)d_in[19];
  const float* Wxs  = (const float*)d_in[20];
  const float* bxs  = (const float*)d_in[21];

  float* ws = (float*)d_ws;
  uint32* wq1   = (uint32*)(ws + 0);        // 98304
  uint32* wq2   = (uint32*)(ws + 98304);    // 98304
  uint32* wq3   = (uint32*)(ws + 196608);   // 98304
  uint32* wih1t = (uint32*)(ws + 294912);   // 12288
  uint32* wih2t = (uint32*)(ws + 307200);   // 1536
  uint32* wih3t = (uint32*)(ws + 308736);   // 1536
  float*  wz1t  = ws + 310272;              // 2304
  float*  wz2t  = ws + 312576;              // 2304
  uint32* wxp   = (uint32*)(ws + 314880);   // 8192
  float*  zx    = ws + 323072;              // 2097152  [L][B][8]
  uint32* zbuf  = (uint32*)(ws + 2420224);  // 524288   [L][B] f16x2 pairs

  float* out = (float*)d_out;  // [B*L*F] y_loc, then recon, kld
  hipMemsetAsync(out + 8388608, 0, 8, stream);

  prep_kernel<<<128, 256, 0, stream>>>(Wih1, Whh1, Wih2, Whh2, Wih3, Whh3,
                                       Wzl, Wzs, Wxl, Wxs,
                                       wq1, wq2, wq3, wih1t, wih2t, wih3t,
                                       wz1t, wz2t, wxp);
  enc_kernel<<<128, 256, 0, stream>>>(x, bih1, bhh1, wq1, wih1t, wz2t, zx);
  decA_kernel<<<128, 256, 0, stream>>>(eps, bih2, bhh2, wq2, wih2t, wz1t,
                                       bzl, bzs, zx, (uint16*)zbuf, out + 8388609);
  decB_kernel<<<128, 256, 0, stream>>>(x, bih3, bhh3, wq3, wih3t, wxp,
                                       bxl, bxs, zbuf, out, out + 8388608);
}

// Round 6
// 11846.373 us; speedup vs baseline: 1.7739x; 1.7529x over previous
//
#include <hip/hip_runtime.h>

// RVAE on MI355X. Design notes (KERNEL-tier):
//  - 128 persistent WGs (one per batch row). Recurrent weights (768x256 f16)
//    register-resident with a K-SPLIT: 512 thr/WG (8 waves, 2 waves/SIMD),
//    thread (kh,kr) owns 3 gate-rows x 128-col half = 48 NAMED uint4 = 192
//    weight VGPRs (+~50 temps ~= 242 <= 256).
//  - WHY: gfx950 wave64 caps ARCH VGPRs at 256. R2-R5's 3-rows-x-256-col
//    design needed 384+50 regs -> forced spill (VGPR_Count=220 invariant
//    under __launch_bounds__ and amdgpu_waves_per_eu; 20.8ms, VALUBusy 17%).
//    No attribute can beat the architectural cap; only footprint reduction.
//  - K-halves combine via 4KB LDS 'part' buffer (r/z combined; n-gate input
//    vs hidden parts SEPARATE, since n = tanh(i_n + r*(bhh_n + h_n))).
//  - NAMED vars, not arrays: R1 showed unrolled arrays -> alloca -> scratch.
//  - All matvecs v_dot2_f32_f16 (f16 pairs, f32 acc); gates/reductions f32.
//    absmax 0.0078 vs 2.5e5 threshold.
//  - Encoder fuses xh -> Wz[:,H:2H] projection so xh[L,B,256] (268MB) is
//    never materialized. decA/decB split: Whh2+Whh3 don't co-fit.

typedef unsigned int uint32;
typedef unsigned short uint16;
typedef _Float16 half2v __attribute__((ext_vector_type(2)));

#define LOG2PI_F 1.8378770664093453f

__device__ __forceinline__ float dot2f(uint32 w, uint32 h, float acc) {
#if __has_builtin(__builtin_amdgcn_fdot2)
  return __builtin_amdgcn_fdot2(__builtin_bit_cast(half2v, w),
                                __builtin_bit_cast(half2v, h), acc, false);
#else
  half2v a = __builtin_bit_cast(half2v, w);
  half2v b = __builtin_bit_cast(half2v, h);
  return acc + (float)a.x * (float)b.x + (float)a.y * (float)b.y;
#endif
}

__device__ __forceinline__ uint32 packh2(float a, float b) {
  half2v v;
  v.x = (_Float16)a;
  v.y = (_Float16)b;
  return __builtin_bit_cast(uint32, v);
}

__device__ __forceinline__ float wredsum64(float v) {
  v += __shfl_xor(v, 32); v += __shfl_xor(v, 16); v += __shfl_xor(v, 8);
  v += __shfl_xor(v, 4);  v += __shfl_xor(v, 2);  v += __shfl_xor(v, 1);
  return v;
}

__device__ __forceinline__ float sigm(float x) { return 1.0f / (1.0f + expf(-x)); }
__device__ __forceinline__ float tanh_(float x) { return 1.0f - 2.0f / (expf(2.0f * x) + 1.0f); }

#define R16(M) M(0) M(1) M(2) M(3) M(4) M(5) M(6) M(7) M(8) M(9) M(10) M(11) \
  M(12) M(13) M(14) M(15)

// 48 named uint4s: 3 gate-rows (r,z,n) x 16 uint4 (128 cols) each.
#define LDW(n) uint4 u##n = uq4[n]; uint4 v##n = vq4[n]; uint4 w##n = nq4[n];

// 12 dot2 per chunk; hv is wave-uniform LDS broadcast (conflict-free).
#define HDOT(n) { uint4 hv = hq4[n]; \
  ar0 = dot2f(u##n.x, hv.x, ar0); ar1 = dot2f(u##n.y, hv.y, ar1); \
  ar0 = dot2f(u##n.z, hv.z, ar0); ar1 = dot2f(u##n.w, hv.w, ar1); \
  az0 = dot2f(v##n.x, hv.x, az0); az1 = dot2f(v##n.y, hv.y, az1); \
  az0 = dot2f(v##n.z, hv.z, az0); az1 = dot2f(v##n.w, hv.w, az1); \
  an0 = dot2f(w##n.x, hv.x, an0); an1 = dot2f(w##n.y, hv.y, an1); \
  an0 = dot2f(w##n.z, hv.z, an0); an1 = dot2f(w##n.w, hv.w, an1); }

#define KPIN __launch_bounds__(512) __attribute__((amdgpu_waves_per_eu(2, 2)))

// ---------------- prep: repack weights into ws ----------------
// wq1/2/3: [768 rows][128 pairs] uint32 = packh2(Whh[k][2i], Whh[k][2i+1])
// wih1t: [16][768] f16x2 pairs of Wih1; wih2t/wih3t: [2][768]
// wz1t/wz2t: [256][9] f32 (pad col for bank spread)
// wxp: [128][64] f16x2 pairs over i of (Wxl;Wxs)
__global__ void prep_kernel(const float* __restrict__ Wih1, const float* __restrict__ Whh1,
                            const float* __restrict__ Wih2, const float* __restrict__ Whh2,
                            const float* __restrict__ Wih3, const float* __restrict__ Whh3,
                            const float* __restrict__ Wzl, const float* __restrict__ Wzs,
                            const float* __restrict__ Wxl, const float* __restrict__ Wxs,
                            uint32* wq1, uint32* wq2, uint32* wq3,
                            uint32* wih1t, uint32* wih2t, uint32* wih3t,
                            float* wz1t, float* wz2t, uint32* wxp) {
  int id = blockIdx.x * blockDim.x + threadIdx.x;
  int str = gridDim.x * blockDim.x;
  for (int n = id; n < 768 * 128; n += str) {
    int k = n >> 7, i = n & 127;
    wq1[n] = packh2(Whh1[k * 256 + 2 * i], Whh1[k * 256 + 2 * i + 1]);
    wq2[n] = packh2(Whh2[k * 256 + 2 * i], Whh2[k * 256 + 2 * i + 1]);
    wq3[n] = packh2(Whh3[k * 256 + 2 * i], Whh3[k * 256 + 2 * i + 1]);
  }
  for (int n = id; n < 16 * 768; n += str) {
    int i = n / 768, k = n % 768;
    wih1t[n] = packh2(Wih1[k * 32 + 2 * i], Wih1[k * 32 + 2 * i + 1]);
  }
  for (int n = id; n < 2 * 768; n += str) {
    int i = n / 768, k = n % 768;
    wih2t[n] = packh2(Wih2[k * 4 + 2 * i], Wih2[k * 4 + 2 * i + 1]);
    wih3t[n] = packh2(Wih3[k * 4 + 2 * i], Wih3[k * 4 + 2 * i + 1]);
  }
  for (int n = id; n < 256 * 8; n += str) {
    int i = n >> 3, o = n & 7;
    wz1t[i * 9 + o] = (o < 4) ? Wzl[o * 512 + i] : Wzs[(o - 4) * 512 + i];
    wz2t[i * 9 + o] = (o < 4) ? Wzl[o * 512 + 256 + i] : Wzs[(o - 4) * 512 + 256 + i];
  }
  for (int n = id; n < 128 * 64; n += str) {
    int i2 = n >> 6, o = n & 63;
    float a = (o < 32) ? Wxl[o * 256 + 2 * i2] : Wxs[(o - 32) * 256 + 2 * i2];
    float b = (o < 32) ? Wxl[o * 256 + 2 * i2 + 1] : Wxs[(o - 32) * 256 + 2 * i2 + 1];
    wxp[n] = packh2(a, b);
  }
}

// ---------------- encoder: reverse GRU + fused xh->Wz projection ----------------
__global__ KPIN void enc_kernel(
    const float* __restrict__ x, const float* __restrict__ bih1,
    const float* __restrict__ bhh1, const uint32* __restrict__ wq1,
    const uint32* __restrict__ wih1t, const float* __restrict__ wz2t,
    float* __restrict__ zx) {
  const int b = blockIdx.x, j = threadIdx.x;
  const int kh = j >> 8, kr = j & 255;
  __shared__ uint32 wih[16 * 768];          // 48KB
  __shared__ float wz[256 * 9];             // 9KB
  __shared__ float h[256];
  __shared__ __align__(16) uint32 hpk[128];
  __shared__ uint32 xpk[16];
  __shared__ float part[4 * 256];           // kh=1 partials: r, z, n_in, n_h

  const uint4* uq4 = (const uint4*)(wq1 + (size_t)kr * 128 + kh * 64);
  const uint4* vq4 = (const uint4*)(wq1 + (size_t)(kr + 256) * 128 + kh * 64);
  const uint4* nq4 = (const uint4*)(wq1 + (size_t)(kr + 512) * 128 + kh * 64);
  const uint4* hq4 = (const uint4*)hpk + kh * 16;
  R16(LDW)
  float bir = 0.f, biz = 0.f, bin = 0.f, bhr = 0.f, bhz = 0.f, bhn = 0.f;
  if (kh == 0) {
    bir = bih1[kr]; biz = bih1[kr + 256]; bin = bih1[kr + 512];
    bhr = bhh1[kr]; bhz = bhh1[kr + 256]; bhn = bhh1[kr + 512];
  }
  for (int i = j; i < 16 * 768; i += 512) wih[i] = wih1t[i];
  for (int i = j; i < 256 * 9; i += 512) wz[i] = wz2t[i];
  float h_reg = 0.0f;
  if (j < 256) h[j] = 0.0f;
  if (j < 128) hpk[j] = 0u;
  const float* xb = x + (size_t)b * (2048 * 32);
  if (j < 16) xpk[j] = packh2(xb[2047 * 32 + 2 * j], xb[2047 * 32 + 2 * j + 1]);
  __syncthreads();

  for (int t = 2047; t >= 0; --t) {
    // ---- prefetch next x (j<16, hidden under dots) ----
    float xn0 = 0.f, xn1 = 0.f;
    if (j < 16 && t > 0) { xn0 = xb[(t - 1) * 32 + 2 * j]; xn1 = xb[(t - 1) * 32 + 2 * j + 1]; }
    // ---- dots over this thread's K-half ----
    float xr = 0.f, xz = 0.f, xn_ = 0.f;
#pragma unroll
    for (int i = 0; i < 8; ++i) {
      int ii = kh * 8 + i;
      uint32 xv = xpk[ii];
      xr = dot2f(wih[ii * 768 + kr], xv, xr);
      xz = dot2f(wih[ii * 768 + 256 + kr], xv, xz);
      xn_ = dot2f(wih[ii * 768 + 512 + kr], xv, xn_);
    }
    float ar0 = 0.f, ar1 = 0.f, az0 = 0.f, az1 = 0.f, an0 = 0.f, an1 = 0.f;
    R16(HDOT)
    if (kh) {
      part[kr] = xr + ar0 + ar1;
      part[256 + kr] = xz + az0 + az1;
      part[512 + kr] = xn_;
      part[768 + kr] = an0 + an1;
    }
    __syncthreads();  // B1: dots done, partials visible
    // ---- gates (kh=0 threads) + state update + x staging ----
    if (kh == 0) {
      float r = sigm(xr + ar0 + ar1 + part[kr] + bir + bhr);
      float zg = sigm(xz + az0 + az1 + part[256 + kr] + biz + bhz);
      float n = tanh_(xn_ + part[512 + kr] + bin + r * (bhn + an0 + an1 + part[768 + kr]));
      float hn = (1.0f - zg) * n + zg * h_reg;
      h_reg = hn;
      h[kr] = hn;
      float ho = __shfl_xor(hn, 1);
      if (!(kr & 1)) hpk[kr >> 1] = packh2(hn, ho);
      if (j < 16 && t > 0) xpk[j] = packh2(xn0, xn1);
    }
    __syncthreads();  // B2: new h/hpk/xpk visible
    // ---- fused projection: wave wv -> output wv (8 waves, 8 outputs) ----
    {
      int wv = j >> 6, l = j & 63;
      float s = 0.f;
#pragma unroll
      for (int m = 0; m < 4; ++m) s += h[l + 64 * m] * wz[(l + 64 * m) * 9 + wv];
      s = wredsum64(s);
      if (l == 0) zx[((size_t)t * 128 + b) * 8 + wv] = s;
    }
    // no loop-end barrier: next writes (part after dots; h after B1) are safe
  }
}

// ---------------- decoder stage A: phi GRU + z sample + kld ----------------
__global__ KPIN void decA_kernel(
    const float* __restrict__ eps, const float* __restrict__ bih2,
    const float* __restrict__ bhh2, const uint32* __restrict__ wq2,
    const uint32* __restrict__ wih2t, const float* __restrict__ wz1t,
    const float* __restrict__ bzl, const float* __restrict__ bzs,
    const float* __restrict__ zx, uint16* __restrict__ zbuf16,
    float* __restrict__ kld_out) {
  const int b = blockIdx.x, j = threadIdx.x;
  const int kh = j >> 8, kr = j & 255;
  const int wv = j >> 6, l = j & 63;
  __shared__ uint32 wih[2 * 768];
  __shared__ float wz[256 * 9];
  __shared__ float h[256];
  __shared__ __align__(16) uint32 hpk[128];
  __shared__ float part[4 * 256];
  __shared__ __align__(8) uint16 zpk16[4];

  const uint4* uq4 = (const uint4*)(wq2 + (size_t)kr * 128 + kh * 64);
  const uint4* vq4 = (const uint4*)(wq2 + (size_t)(kr + 256) * 128 + kh * 64);
  const uint4* nq4 = (const uint4*)(wq2 + (size_t)(kr + 512) * 128 + kh * 64);
  const uint4* hq4 = (const uint4*)hpk + kh * 16;
  R16(LDW)
  float bir = 0.f, biz = 0.f, bin = 0.f, bhr = 0.f, bhz = 0.f, bhn = 0.f;
  if (kh == 0) {
    bir = bih2[kr]; biz = bih2[kr + 256]; bin = bih2[kr + 512];
    bhr = bhh2[kr]; bhz = bhh2[kr + 256]; bhn = bhh2[kr + 512];
  }
  float bzlr = 0.f, bzsr = 0.f;
  if (wv < 4 && l == 0) { bzlr = bzl[wv]; bzsr = bzs[wv]; }
  for (int i = j; i < 2 * 768; i += 512) wih[i] = wih2t[i];
  for (int i = j; i < 256 * 9; i += 512) wz[i] = wz1t[i];
  float h_reg = 0.0f, kacc = 0.0f;
  if (j < 256) h[j] = 0.0f;
  if (j < 128) hpk[j] = 0u;
  if (j < 4) zpk16[j] = (uint16)0;
  __syncthreads();

  for (int t = 0; t < 2048; ++t) {
    const size_t tb = (size_t)t * 128 + b;
    // ---- prefetch (lane0 of waves 0..3; hidden under dots) ----
    float ev = 0.f, zxa = 0.f, zxb = 0.f;
    if (wv < 4 && l == 0) { ev = eps[tb * 4 + wv]; zxa = zx[tb * 8 + wv]; zxb = zx[tb * 8 + wv + 4]; }
    // ---- dots ----
    uint32 zi = ((const uint32*)zpk16)[kh];
    float xr = dot2f(wih[kh * 768 + kr], zi, 0.f);
    float xz = dot2f(wih[kh * 768 + 256 + kr], zi, 0.f);
    float xn_ = dot2f(wih[kh * 768 + 512 + kr], zi, 0.f);
    float ar0 = 0.f, ar1 = 0.f, az0 = 0.f, az1 = 0.f, an0 = 0.f, an1 = 0.f;
    R16(HDOT)
    if (kh) {
      part[kr] = xr + ar0 + ar1;
      part[256 + kr] = xz + az0 + az1;
      part[512 + kr] = xn_;
      part[768 + kr] = an0 + an1;
    }
    __syncthreads();  // B1
    if (kh == 0) {
      float r = sigm(xr + ar0 + ar1 + part[kr] + bir + bhr);
      float zg = sigm(xz + az0 + az1 + part[256 + kr] + biz + bhz);
      float n = tanh_(xn_ + part[512 + kr] + bin + r * (bhn + an0 + an1 + part[768 + kr]));
      float hn = (1.0f - zg) * n + zg * h_reg;
      h_reg = hn;
      h[kr] = hn;
      float ho = __shfl_xor(hn, 1);
      if (!(kr & 1)) hpk[kr >> 1] = packh2(hn, ho);
    }
    __syncthreads();  // B2
    // ---- z proj: wave wv (0..3) -> loc[wv], logvar[wv]; lane0 samples ----
    if (wv < 4) {
      float s0 = 0.f, s1 = 0.f;
#pragma unroll
      for (int m = 0; m < 4; ++m) {
        float hv = h[l + 64 * m];
        const float* wr_ = &wz[(l + 64 * m) * 9];
        s0 += hv * wr_[wv];
        s1 += hv * wr_[wv + 4];
      }
      s0 = wredsum64(s0);
      s1 = wredsum64(s1);
      if (l == 0) {
        float loc = s0 + bzlr + zxa;
        float lv = s1 + bzsr + zxb;
        float sc = expf(0.5f * lv);
        float zv = loc + sc * ev;
        kacc += 0.5f * (sc * sc + loc * loc - 1.0f - lv);
        uint16 hz = __builtin_bit_cast(uint16, (_Float16)zv);
        zpk16[wv] = hz;
        zbuf16[tb * 4 + wv] = hz;
      }
    }
    __syncthreads();  // B3: zpk16 ready for next dots
  }
  if (wv < 4 && l == 0) atomicAdd(kld_out, kacc);
}

// ---------------- decoder stage B: theta GRU + x linears + recon ----------------
__global__ KPIN void decB_kernel(
    const float* __restrict__ x, const float* __restrict__ bih3,
    const float* __restrict__ bhh3, const uint32* __restrict__ wq3,
    const uint32* __restrict__ wih3t, const uint32* __restrict__ wxp_g,
    const float* __restrict__ bxl, const float* __restrict__ bxs,
    const uint32* __restrict__ zbuf, float* __restrict__ y,
    float* __restrict__ recon_out) {
  const int b = blockIdx.x, j = threadIdx.x;
  const int kh = j >> 8, kr = j & 255;
  const int oo = j >> 3, qq = j & 7;
  __shared__ uint32 wih[2 * 768];
  __shared__ uint32 wxpL[128 * 65];          // padded: bank-spread
  __shared__ __align__(16) uint32 hpk[128];
  __shared__ float part[4 * 256];
  __shared__ float xl[64];
  __shared__ uint32 zpk[2];

  const uint4* uq4 = (const uint4*)(wq3 + (size_t)kr * 128 + kh * 64);
  const uint4* vq4 = (const uint4*)(wq3 + (size_t)(kr + 256) * 128 + kh * 64);
  const uint4* nq4 = (const uint4*)(wq3 + (size_t)(kr + 512) * 128 + kh * 64);
  const uint4* hq4 = (const uint4*)hpk + kh * 16;
  R16(LDW)
  float bir = 0.f, biz = 0.f, bin = 0.f, bhr = 0.f, bhz = 0.f, bhn = 0.f;
  if (kh == 0) {
    bir = bih3[kr]; biz = bih3[kr + 256]; bin = bih3[kr + 512];
    bhr = bhh3[kr]; bhz = bhh3[kr + 256]; bhn = bhh3[kr + 512];
  }
  float bx_r = 0.f;
  if (qq == 0) bx_r = (oo < 32) ? bxl[oo] : bxs[oo - 32];
  for (int i = j; i < 128 * 64; i += 512) wxpL[(i >> 6) * 65 + (i & 63)] = wxp_g[i];
  for (int i = j; i < 2 * 768; i += 512) wih[i] = wih3t[i];
  float h_reg = 0.0f, racc = 0.0f;
  if (j < 128) hpk[j] = 0u;
  if (j < 2) zpk[j] = zbuf[(size_t)b * 2 + j];  // t = 0
  const float* xb = x + (size_t)b * (2048 * 32);
  float* yb = y + (size_t)b * (2048 * 32);
  __syncthreads();

  for (int t = 0; t < 2048; ++t) {
    // ---- prefetch ----
    float xv = 0.f;
    uint32 zn = 0u;
    if (j < 32) xv = xb[t * 32 + j];
    if (j < 2 && t + 1 < 2048) zn = zbuf[((size_t)(t + 1) * 128 + b) * 2 + j];
    // ---- dots ----
    uint32 zi = zpk[kh];
    float xr = dot2f(wih[kh * 768 + kr], zi, 0.f);
    float xz = dot2f(wih[kh * 768 + 256 + kr], zi, 0.f);
    float xn_ = dot2f(wih[kh * 768 + 512 + kr], zi, 0.f);
    float ar0 = 0.f, ar1 = 0.f, az0 = 0.f, az1 = 0.f, an0 = 0.f, an1 = 0.f;
    R16(HDOT)
    if (kh) {
      part[kr] = xr + ar0 + ar1;
      part[256 + kr] = xz + az0 + az1;
      part[512 + kr] = xn_;
      part[768 + kr] = an0 + an1;
    }
    __syncthreads();  // B1
    if (kh == 0) {
      float r = sigm(xr + ar0 + ar1 + part[kr] + bir + bhr);
      float zg = sigm(xz + az0 + az1 + part[256 + kr] + biz + bhz);
      float n = tanh_(xn_ + part[512 + kr] + bin + r * (bhn + an0 + an1 + part[768 + kr]));
      float hn = (1.0f - zg) * n + zg * h_reg;
      h_reg = hn;
      float ho = __shfl_xor(hn, 1);
      if (!(kr & 1)) hpk[kr >> 1] = packh2(hn, ho);
      if (j < 2 && t + 1 < 2048) zpk[j] = zn;
    }
    __syncthreads();  // B2
    // ---- x-linear: (o,q) = (j>>3, j&7); 8-way K-split, 16 dot2 each ----
    {
      float s = 0.f;
#pragma unroll
      for (int m = 0; m < 16; ++m) {
        int i2 = qq + 8 * m;
        s = dot2f(wxpL[i2 * 65 + oo], hpk[i2], s);
      }
      s += __shfl_xor(s, 4);
      s += __shfl_xor(s, 2);
      s += __shfl_xor(s, 1);
      if (qq == 0) xl[oo] = s + bx_r;
    }
    __syncthreads();  // B3: xl ready
    // ---- recon + y write (threads 0..31) ----
    if (j < 32) {
      float loc = xl[j], lv = xl[j + 32];
      yb[t * 32 + j] = loc;
      float d = xv - loc;
      racc += 0.5f * d * d * expf(-lv) + 0.5f * lv + 0.5f * LOG2PI_F;
    }
    // no loop-end barrier: next part/hpk/zpk writes ordered by B1(t+1)/B2(t+1)
  }
  if (j < 32) {
    racc += __shfl_xor(racc, 16); racc += __shfl_xor(racc, 8);
    racc += __shfl_xor(racc, 4);  racc += __shfl_xor(racc, 2);
    racc += __shfl_xor(racc, 1);
    if (j == 0) atomicAdd(recon_out, racc);
  }
}

// ---------------- launcher ----------------
extern "C" void kernel_launch(void* const* d_in, const int* in_sizes, int n_in,
                              void* d_out, int out_size, void* d_ws, size_t ws_size,
                              hipStream_t stream) {
  const float* x    = (const float*)d_in[0];
  const float* eps  = (const float*)d_in[1];
  const float* Wih1 = (const float*)d_in[2];
  const float* Whh1 = (const float*)d_in[3];
  const float* bih1 = (const float*)d_in[4];
  const float* bhh1 = (const float*)d_in[5];
  const float* Wih2 = (const float*)d_in[6];
  const float* Whh2 = (const float*)d_in[7];
  const float* bih2 = (const float*)d_in[8];
  const float* bhh2 = (const float*)d_in[9];
  const float* Wih3 = (const float*)d_in[10];
  const float* Whh3 = (const float*)d_in[11];
  const float* bih3 = (const float*)d_in[12];
  const float* bhh3 = (const float*)d_in[13];
  const float* Wzl  = (const float*)d_in[14];
  const float* bzl  = (const float*)d_in[15];
  const float* Wzs  = (const float*)d_in[16];
  const float* bzs  = (const float*)d_in[17];
  const float* Wxl  = (const float*)d_in[18];
  const float* bxl  = (const float*)d_in[19];
  const float* Wxs  = (const float*)d_in[20];
  const float* bxs  = (const float*)d_in[21];

  float* ws = (float*)d_ws;
  uint32* wq1   = (uint32*)(ws + 0);        // 98304
  uint32* wq2   = (uint32*)(ws + 98304);    // 98304
  uint32* wq3   = (uint32*)(ws + 196608);   // 98304
  uint32* wih1t = (uint32*)(ws + 294912);   // 12288
  uint32* wih2t = (uint32*)(ws + 307200);   // 1536
  uint32* wih3t = (uint32*)(ws + 308736);   // 1536
  float*  wz1t  = ws + 310272;              // 2304
  float*  wz2t  = ws + 312576;              // 2304
  uint32* wxp   = (uint32*)(ws + 314880);   // 8192
  float*  zx    = ws + 323072;              // 2097152  [L][B][8]
  uint32* zbuf  = (uint32*)(ws + 2420224);  // 524288   [L][B] f16x2 pairs

  float* out = (float*)d_out;  // [B*L*F] y_loc, then recon, kld
  hipMemsetAsync(out + 8388608, 0, 8, stream);

  prep_kernel<<<128, 256, 0, stream>>>(Wih1, Whh1, Wih2, Whh2, Wih3, Whh3,
                                       Wzl, Wzs, Wxl, Wxs,
                                       wq1, wq2, wq3, wih1t, wih2t, wih3t,
                                       wz1t, wz2t, wxp);
  enc_kernel<<<128, 512, 0, stream>>>(x, bih1, bhh1, wq1, wih1t, wz2t, zx);
  decA_kernel<<<128, 512, 0, stream>>>(eps, bih2, bhh2, wq2, wih2t, wz1t,
                                       bzl, bzs, zx, (uint16*)zbuf, out + 8388609);
  decB_kernel<<<128, 512, 0, stream>>>(x, bih3, bhh3, wq3, wih3t, wxp,
                                       bxl, bxs, zbuf, out, out + 8388608);
}

// Round 7
// 11699.554 us; speedup vs baseline: 1.7962x; 1.0125x over previous
//
#include <hip/hip_runtime.h>

// RVAE on MI355X. Design notes (KERNEL-tier):
//  - 128 persistent WGs (one per batch row). Recurrent weights (768x256 f16)
//    register-resident with a K-SPLIT: 512 thr/WG (8 waves, 2 waves/SIMD),
//    thread (kh,kr) owns 3 gate-rows x 128-col half = 48 NAMED uint4 = 192
//    weight regs (unified VGPR+AGPR; R6: VGPR_Count=128 + accum, no scratch).
//  - WHY: gfx950 wave64 caps ARCH VGPRs at 256; 384-reg designs force spill
//    (R2-R5: VGPR=220 invariant, 20.8ms). Footprint reduction, not attributes.
//  - K-halves combine via 4KB LDS 'part' buffer (n-gate input/hidden parts
//    separate: n = tanh(i_n + r*(bhh_n + h_n))).
//  - NAMED vars, not arrays: unrolled arrays -> alloca -> scratch (R1).
//  - decB x-linear weights ALSO in registers (16 uint32/thread): R6's LDS
//    wxpL[i2*65+oo] was an 8-way bank conflict (2.01e8 SQ_LDS_BANK_CONFLICT,
//    bank=(qq+8m+oo)%32 — padding fixed the wrong axis). Registers kill the
//    conflicts AND the xl[]/B3 round-trip (loc/lv paired via shfl_xor(8)).
//  - All matvecs v_dot2_f32_f16 (f16 pairs, f32 acc); gates/reductions f32.
//    absmax 0.0078 vs 2.5e5 threshold.
//  - Encoder fuses xh -> Wz[:,H:2H] projection so xh[L,B,256] (268MB) is
//    never materialized. decA/decB split: Whh2+Whh3 don't co-fit.

typedef unsigned int uint32;
typedef unsigned short uint16;
typedef _Float16 half2v __attribute__((ext_vector_type(2)));

#define LOG2PI_F 1.8378770664093453f

__device__ __forceinline__ float dot2f(uint32 w, uint32 h, float acc) {
#if __has_builtin(__builtin_amdgcn_fdot2)
  return __builtin_amdgcn_fdot2(__builtin_bit_cast(half2v, w),
                                __builtin_bit_cast(half2v, h), acc, false);
#else
  half2v a = __builtin_bit_cast(half2v, w);
  half2v b = __builtin_bit_cast(half2v, h);
  return acc + (float)a.x * (float)b.x + (float)a.y * (float)b.y;
#endif
}

__device__ __forceinline__ uint32 packh2(float a, float b) {
  half2v v;
  v.x = (_Float16)a;
  v.y = (_Float16)b;
  return __builtin_bit_cast(uint32, v);
}

__device__ __forceinline__ float wredsum64(float v) {
  v += __shfl_xor(v, 32); v += __shfl_xor(v, 16); v += __shfl_xor(v, 8);
  v += __shfl_xor(v, 4);  v += __shfl_xor(v, 2);  v += __shfl_xor(v, 1);
  return v;
}

__device__ __forceinline__ float sigm(float x) { return 1.0f / (1.0f + expf(-x)); }
__device__ __forceinline__ float tanh_(float x) { return 1.0f - 2.0f / (expf(2.0f * x) + 1.0f); }

#define R16(M) M(0) M(1) M(2) M(3) M(4) M(5) M(6) M(7) M(8) M(9) M(10) M(11) \
  M(12) M(13) M(14) M(15)

// 48 named uint4s: 3 gate-rows (r,z,n) x 16 uint4 (128 cols) each.
#define LDW(n) uint4 u##n = uq4[n]; uint4 v##n = vq4[n]; uint4 w##n = nq4[n];

// 12 dot2 per chunk; hv is wave-uniform LDS broadcast (conflict-free).
#define HDOT(n) { uint4 hv = hq4[n]; \
  ar0 = dot2f(u##n.x, hv.x, ar0); ar1 = dot2f(u##n.y, hv.y, ar1); \
  ar0 = dot2f(u##n.z, hv.z, ar0); ar1 = dot2f(u##n.w, hv.w, ar1); \
  az0 = dot2f(v##n.x, hv.x, az0); az1 = dot2f(v##n.y, hv.y, az1); \
  az0 = dot2f(v##n.z, hv.z, az0); az1 = dot2f(v##n.w, hv.w, az1); \
  an0 = dot2f(w##n.x, hv.x, an0); an1 = dot2f(w##n.y, hv.y, an1); \
  an0 = dot2f(w##n.z, hv.z, an0); an1 = dot2f(w##n.w, hv.w, an1); }

// decB x-linear: 16 named weight regs + 16 broadcast hpk reads.
#define LDXW(n) uint32 xw##n = wxp_g[(qq + 8 * n) * 64 + fo];
#define XDOT(n) s = dot2f(xw##n, hpk[qq + 8 * n], s);

#define KPIN __launch_bounds__(512) __attribute__((amdgpu_waves_per_eu(2, 2)))

// ---------------- prep: repack weights into ws ----------------
// wq1/2/3: [768 rows][128 pairs] uint32 = packh2(Whh[k][2i], Whh[k][2i+1])
// wih1t: [16][768] f16x2 pairs of Wih1; wih2t/wih3t: [2][768]
// wz1t/wz2t: [256][9] f32 (pad col for bank spread)
// wxp: [128][64] f16x2 pairs over i of (Wxl;Wxs)
__global__ void prep_kernel(const float* __restrict__ Wih1, const float* __restrict__ Whh1,
                            const float* __restrict__ Wih2, const float* __restrict__ Whh2,
                            const float* __restrict__ Wih3, const float* __restrict__ Whh3,
                            const float* __restrict__ Wzl, const float* __restrict__ Wzs,
                            const float* __restrict__ Wxl, const float* __restrict__ Wxs,
                            uint32* wq1, uint32* wq2, uint32* wq3,
                            uint32* wih1t, uint32* wih2t, uint32* wih3t,
                            float* wz1t, float* wz2t, uint32* wxp) {
  int id = blockIdx.x * blockDim.x + threadIdx.x;
  int str = gridDim.x * blockDim.x;
  for (int n = id; n < 768 * 128; n += str) {
    int k = n >> 7, i = n & 127;
    wq1[n] = packh2(Whh1[k * 256 + 2 * i], Whh1[k * 256 + 2 * i + 1]);
    wq2[n] = packh2(Whh2[k * 256 + 2 * i], Whh2[k * 256 + 2 * i + 1]);
    wq3[n] = packh2(Whh3[k * 256 + 2 * i], Whh3[k * 256 + 2 * i + 1]);
  }
  for (int n = id; n < 16 * 768; n += str) {
    int i = n / 768, k = n % 768;
    wih1t[n] = packh2(Wih1[k * 32 + 2 * i], Wih1[k * 32 + 2 * i + 1]);
  }
  for (int n = id; n < 2 * 768; n += str) {
    int i = n / 768, k = n % 768;
    wih2t[n] = packh2(Wih2[k * 4 + 2 * i], Wih2[k * 4 + 2 * i + 1]);
    wih3t[n] = packh2(Wih3[k * 4 + 2 * i], Wih3[k * 4 + 2 * i + 1]);
  }
  for (int n = id; n < 256 * 8; n += str) {
    int i = n >> 3, o = n & 7;
    wz1t[i * 9 + o] = (o < 4) ? Wzl[o * 512 + i] : Wzs[(o - 4) * 512 + i];
    wz2t[i * 9 + o] = (o < 4) ? Wzl[o * 512 + 256 + i] : Wzs[(o - 4) * 512 + 256 + i];
  }
  for (int n = id; n < 128 * 64; n += str) {
    int i2 = n >> 6, o = n & 63;
    float a = (o < 32) ? Wxl[o * 256 + 2 * i2] : Wxs[(o - 32) * 256 + 2 * i2];
    float b = (o < 32) ? Wxl[o * 256 + 2 * i2 + 1] : Wxs[(o - 32) * 256 + 2 * i2 + 1];
    wxp[n] = packh2(a, b);
  }
}

// ---------------- encoder: reverse GRU + fused xh->Wz projection ----------------
__global__ KPIN void enc_kernel(
    const float* __restrict__ x, const float* __restrict__ bih1,
    const float* __restrict__ bhh1, const uint32* __restrict__ wq1,
    const uint32* __restrict__ wih1t, const float* __restrict__ wz2t,
    float* __restrict__ zx) {
  const int b = blockIdx.x, j = threadIdx.x;
  const int kh = j >> 8, kr = j & 255;
  __shared__ uint32 wih[16 * 768];          // 48KB
  __shared__ float wz[256 * 9];             // 9KB
  __shared__ float h[256];
  __shared__ __align__(16) uint32 hpk[128];
  __shared__ uint32 xpk[16];
  __shared__ float part[4 * 256];           // kh=1 partials: r, z, n_in, n_h

  const uint4* uq4 = (const uint4*)(wq1 + (size_t)kr * 128 + kh * 64);
  const uint4* vq4 = (const uint4*)(wq1 + (size_t)(kr + 256) * 128 + kh * 64);
  const uint4* nq4 = (const uint4*)(wq1 + (size_t)(kr + 512) * 128 + kh * 64);
  const uint4* hq4 = (const uint4*)hpk + kh * 16;
  R16(LDW)
  float bir = 0.f, biz = 0.f, bin = 0.f, bhr = 0.f, bhz = 0.f, bhn = 0.f;
  if (kh == 0) {
    bir = bih1[kr]; biz = bih1[kr + 256]; bin = bih1[kr + 512];
    bhr = bhh1[kr]; bhz = bhh1[kr + 256]; bhn = bhh1[kr + 512];
  }
  for (int i = j; i < 16 * 768; i += 512) wih[i] = wih1t[i];
  for (int i = j; i < 256 * 9; i += 512) wz[i] = wz2t[i];
  float h_reg = 0.0f;
  if (j < 256) h[j] = 0.0f;
  if (j < 128) hpk[j] = 0u;
  const float* xb = x + (size_t)b * (2048 * 32);
  if (j < 16) xpk[j] = packh2(xb[2047 * 32 + 2 * j], xb[2047 * 32 + 2 * j + 1]);
  __syncthreads();

  for (int t = 2047; t >= 0; --t) {
    // ---- prefetch next x (j<16, hidden under dots) ----
    float xn0 = 0.f, xn1 = 0.f;
    if (j < 16 && t > 0) { xn0 = xb[(t - 1) * 32 + 2 * j]; xn1 = xb[(t - 1) * 32 + 2 * j + 1]; }
    // ---- dots over this thread's K-half ----
    float xr = 0.f, xz = 0.f, xn_ = 0.f;
#pragma unroll
    for (int i = 0; i < 8; ++i) {
      int ii = kh * 8 + i;
      uint32 xv = xpk[ii];
      xr = dot2f(wih[ii * 768 + kr], xv, xr);
      xz = dot2f(wih[ii * 768 + 256 + kr], xv, xz);
      xn_ = dot2f(wih[ii * 768 + 512 + kr], xv, xn_);
    }
    float ar0 = 0.f, ar1 = 0.f, az0 = 0.f, az1 = 0.f, an0 = 0.f, an1 = 0.f;
    R16(HDOT)
    if (kh) {
      part[kr] = xr + ar0 + ar1;
      part[256 + kr] = xz + az0 + az1;
      part[512 + kr] = xn_;
      part[768 + kr] = an0 + an1;
    }
    __syncthreads();  // B1: dots done, partials visible
    // ---- gates (kh=0 threads) + state update + x staging ----
    if (kh == 0) {
      float r = sigm(xr + ar0 + ar1 + part[kr] + bir + bhr);
      float zg = sigm(xz + az0 + az1 + part[256 + kr] + biz + bhz);
      float n = tanh_(xn_ + part[512 + kr] + bin + r * (bhn + an0 + an1 + part[768 + kr]));
      float hn = (1.0f - zg) * n + zg * h_reg;
      h_reg = hn;
      h[kr] = hn;
      float ho = __shfl_xor(hn, 1);
      if (!(kr & 1)) hpk[kr >> 1] = packh2(hn, ho);
      if (j < 16 && t > 0) xpk[j] = packh2(xn0, xn1);
    }
    __syncthreads();  // B2: new h/hpk/xpk visible
    // ---- fused projection: wave wv -> output wv (8 waves, 8 outputs) ----
    {
      int wv = j >> 6, l = j & 63;
      float s = 0.f;
#pragma unroll
      for (int m = 0; m < 4; ++m) s += h[l + 64 * m] * wz[(l + 64 * m) * 9 + wv];
      s = wredsum64(s);
      if (l == 0) zx[((size_t)t * 128 + b) * 8 + wv] = s;
    }
    // no loop-end barrier: next writes (part after dots; h after B1) are safe
  }
}

// ---------------- decoder stage A: phi GRU + z sample + kld ----------------
__global__ KPIN void decA_kernel(
    const float* __restrict__ eps, const float* __restrict__ bih2,
    const float* __restrict__ bhh2, const uint32* __restrict__ wq2,
    const uint32* __restrict__ wih2t, const float* __restrict__ wz1t,
    const float* __restrict__ bzl, const float* __restrict__ bzs,
    const float* __restrict__ zx, uint16* __restrict__ zbuf16,
    float* __restrict__ kld_out) {
  const int b = blockIdx.x, j = threadIdx.x;
  const int kh = j >> 8, kr = j & 255;
  const int wv = j >> 6, l = j & 63;
  __shared__ uint32 wih[2 * 768];
  __shared__ float wz[256 * 9];
  __shared__ float h[256];
  __shared__ __align__(16) uint32 hpk[128];
  __shared__ float part[4 * 256];
  __shared__ __align__(8) uint16 zpk16[4];

  const uint4* uq4 = (const uint4*)(wq2 + (size_t)kr * 128 + kh * 64);
  const uint4* vq4 = (const uint4*)(wq2 + (size_t)(kr + 256) * 128 + kh * 64);
  const uint4* nq4 = (const uint4*)(wq2 + (size_t)(kr + 512) * 128 + kh * 64);
  const uint4* hq4 = (const uint4*)hpk + kh * 16;
  R16(LDW)
  float bir = 0.f, biz = 0.f, bin = 0.f, bhr = 0.f, bhz = 0.f, bhn = 0.f;
  if (kh == 0) {
    bir = bih2[kr]; biz = bih2[kr + 256]; bin = bih2[kr + 512];
    bhr = bhh2[kr]; bhz = bhh2[kr + 256]; bhn = bhh2[kr + 512];
  }
  float bzlr = 0.f, bzsr = 0.f;
  if (wv < 4 && l == 0) { bzlr = bzl[wv]; bzsr = bzs[wv]; }
  for (int i = j; i < 2 * 768; i += 512) wih[i] = wih2t[i];
  for (int i = j; i < 256 * 9; i += 512) wz[i] = wz1t[i];
  float h_reg = 0.0f, kacc = 0.0f;
  if (j < 256) h[j] = 0.0f;
  if (j < 128) hpk[j] = 0u;
  if (j < 4) zpk16[j] = (uint16)0;
  __syncthreads();

  for (int t = 0; t < 2048; ++t) {
    const size_t tb = (size_t)t * 128 + b;
    // ---- prefetch (lane0 of waves 0..3; hidden under dots) ----
    float ev = 0.f, zxa = 0.f, zxb = 0.f;
    if (wv < 4 && l == 0) { ev = eps[tb * 4 + wv]; zxa = zx[tb * 8 + wv]; zxb = zx[tb * 8 + wv + 4]; }
    // ---- dots ----
    uint32 zi = ((const uint32*)zpk16)[kh];
    float xr = dot2f(wih[kh * 768 + kr], zi, 0.f);
    float xz = dot2f(wih[kh * 768 + 256 + kr], zi, 0.f);
    float xn_ = dot2f(wih[kh * 768 + 512 + kr], zi, 0.f);
    float ar0 = 0.f, ar1 = 0.f, az0 = 0.f, az1 = 0.f, an0 = 0.f, an1 = 0.f;
    R16(HDOT)
    if (kh) {
      part[kr] = xr + ar0 + ar1;
      part[256 + kr] = xz + az0 + az1;
      part[512 + kr] = xn_;
      part[768 + kr] = an0 + an1;
    }
    __syncthreads();  // B1
    if (kh == 0) {
      float r = sigm(xr + ar0 + ar1 + part[kr] + bir + bhr);
      float zg = sigm(xz + az0 + az1 + part[256 + kr] + biz + bhz);
      float n = tanh_(xn_ + part[512 + kr] + bin + r * (bhn + an0 + an1 + part[768 + kr]));
      float hn = (1.0f - zg) * n + zg * h_reg;
      h_reg = hn;
      h[kr] = hn;
      float ho = __shfl_xor(hn, 1);
      if (!(kr & 1)) hpk[kr >> 1] = packh2(hn, ho);
    }
    __syncthreads();  // B2
    // ---- z proj: wave wv (0..3) -> loc[wv], logvar[wv]; lane0 samples ----
    if (wv < 4) {
      float s0 = 0.f, s1 = 0.f;
#pragma unroll
      for (int m = 0; m < 4; ++m) {
        float hv = h[l + 64 * m];
        const float* wr_ = &wz[(l + 64 * m) * 9];
        s0 += hv * wr_[wv];
        s1 += hv * wr_[wv + 4];
      }
      s0 = wredsum64(s0);
      s1 = wredsum64(s1);
      if (l == 0) {
        float loc = s0 + bzlr + zxa;
        float lv = s1 + bzsr + zxb;
        float sc = expf(0.5f * lv);
        float zv = loc + sc * ev;
        kacc += 0.5f * (sc * sc + loc * loc - 1.0f - lv);
        uint16 hz = __builtin_bit_cast(uint16, (_Float16)zv);
        zpk16[wv] = hz;
        zbuf16[tb * 4 + wv] = hz;
      }
    }
    __syncthreads();  // B3: zpk16 ready for next dots
  }
  if (wv < 4 && l == 0) atomicAdd(kld_out, kacc);
}

// ---------------- decoder stage B: theta GRU + x linears + recon ----------------
__global__ KPIN void decB_kernel(
    const float* __restrict__ x, const float* __restrict__ bih3,
    const float* __restrict__ bhh3, const uint32* __restrict__ wq3,
    const uint32* __restrict__ wih3t, const uint32* __restrict__ wxp_g,
    const float* __restrict__ bxl, const float* __restrict__ bxs,
    const uint32* __restrict__ zbuf, float* __restrict__ y,
    float* __restrict__ recon_out) {
  const int b = blockIdx.x, j = threadIdx.x;
  const int kh = j >> 8, kr = j & 255;
  // x-linear role: qq = K-octant, f = feature, which = 0:loc / 1:logvar.
  // Pairing: lanes j and j^8 hold (loc f, lv f) -> shfl_xor(8), no LDS.
  const int qq = j & 7, g = j >> 3;
  const int f = g >> 1, which = g & 1;
  const int fo = f + 32 * which;
  __shared__ uint32 wih[2 * 768];
  __shared__ __align__(16) uint32 hpk[128];
  __shared__ float part[4 * 256];
  __shared__ uint32 zpk[2];

  const uint4* uq4 = (const uint4*)(wq3 + (size_t)kr * 128 + kh * 64);
  const uint4* vq4 = (const uint4*)(wq3 + (size_t)(kr + 256) * 128 + kh * 64);
  const uint4* nq4 = (const uint4*)(wq3 + (size_t)(kr + 512) * 128 + kh * 64);
  const uint4* hq4 = (const uint4*)hpk + kh * 16;
  R16(LDW)
  R16(LDXW)                                  // 16 x-linear weight regs
  float bir = 0.f, biz = 0.f, bin = 0.f, bhr = 0.f, bhz = 0.f, bhn = 0.f;
  if (kh == 0) {
    bir = bih3[kr]; biz = bih3[kr + 256]; bin = bih3[kr + 512];
    bhr = bhh3[kr]; bhz = bhh3[kr + 256]; bhn = bhh3[kr + 512];
  }
  const float bx_r = (which == 0) ? bxl[f] : bxs[f];
  for (int i = j; i < 2 * 768; i += 512) wih[i] = wih3t[i];
  float h_reg = 0.0f, racc = 0.0f;
  if (j < 128) hpk[j] = 0u;
  if (j < 2) zpk[j] = zbuf[(size_t)b * 2 + j];  // t = 0
  const float* xb = x + (size_t)b * (2048 * 32);
  float* yb = y + (size_t)b * (2048 * 32);
  __syncthreads();

  for (int t = 0; t < 2048; ++t) {
    // ---- prefetch ----
    float xv = 0.f;
    uint32 zn = 0u;
    if (qq == 0 && which == 0) xv = xb[t * 32 + f];
    if (j < 2 && t + 1 < 2048) zn = zbuf[((size_t)(t + 1) * 128 + b) * 2 + j];
    // ---- dots ----
    uint32 zi = zpk[kh];
    float xr = dot2f(wih[kh * 768 + kr], zi, 0.f);
    float xz = dot2f(wih[kh * 768 + 256 + kr], zi, 0.f);
    float xn_ = dot2f(wih[kh * 768 + 512 + kr], zi, 0.f);
    float ar0 = 0.f, ar1 = 0.f, az0 = 0.f, az1 = 0.f, an0 = 0.f, an1 = 0.f;
    R16(HDOT)
    if (kh) {
      part[kr] = xr + ar0 + ar1;
      part[256 + kr] = xz + az0 + az1;
      part[512 + kr] = xn_;
      part[768 + kr] = an0 + an1;
    }
    __syncthreads();  // B1
    if (kh == 0) {
      float r = sigm(xr + ar0 + ar1 + part[kr] + bir + bhr);
      float zg = sigm(xz + az0 + az1 + part[256 + kr] + biz + bhz);
      float n = tanh_(xn_ + part[512 + kr] + bin + r * (bhn + an0 + an1 + part[768 + kr]));
      float hn = (1.0f - zg) * n + zg * h_reg;
      h_reg = hn;
      float ho = __shfl_xor(hn, 1);
      if (!(kr & 1)) hpk[kr >> 1] = packh2(hn, ho);
      if (j < 2 && t + 1 < 2048) zpk[j] = zn;
    }
    __syncthreads();  // B2
    // ---- x-linear from registers; hpk reads are 8-lane broadcasts ----
    {
      float s = 0.f;
      R16(XDOT)
      s += __shfl_xor(s, 4);
      s += __shfl_xor(s, 2);
      s += __shfl_xor(s, 1);     // all 8 lanes of the qq-group hold the sum
      s += bx_r;
      float prt = __shfl_xor(s, 8);  // partner (loc<->lv for same f)
      if (qq == 0 && which == 0) {
        float loc = s, lv = prt;
        yb[t * 32 + f] = loc;
        float d = xv - loc;
        racc += 0.5f * d * d * expf(-lv) + 0.5f * lv + 0.5f * LOG2PI_F;
      }
    }
    // no B3: hpk reads complete before each thread's next B1
  }
  racc = wredsum64(racc);
  if ((j & 63) == 0) atomicAdd(recon_out, racc);
}

// ---------------- launcher ----------------
extern "C" void kernel_launch(void* const* d_in, const int* in_sizes, int n_in,
                              void* d_out, int out_size, void* d_ws, size_t ws_size,
                              hipStream_t stream) {
  const float* x    = (const float*)d_in[0];
  const float* eps  = (const float*)d_in[1];
  const float* Wih1 = (const float*)d_in[2];
  const float* Whh1 = (const float*)d_in[3];
  const float* bih1 = (const float*)d_in[4];
  const float* bhh1 = (const float*)d_in[5];
  const float* Wih2 = (const float*)d_in[6];
  const float* Whh2 = (const float*)d_in[7];
  const float* bih2 = (const float*)d_in[8];
  const float* bhh2 = (const float*)d_in[9];
  const float* Wih3 = (const float*)d_in[10];
  const float* Whh3 = (const float*)d_in[11];
  const float* bih3 = (const float*)d_in[12];
  const float* bhh3 = (const float*)d_in[13];
  const float* Wzl  = (const float*)d_in[14];
  const float* bzl  = (const float*)d_in[15];
  const float* Wzs  = (const float*)d_in[16];
  const float* bzs  = (const float*)d_in[17];
  const float* Wxl  = (const float*)d_in[18];
  const float* bxl  = (const float*)d_in[19];
  const float* Wxs  = (const float*)d_in[20];
  const float* bxs  = (const float*)d_in[21];

  float* ws = (float*)d_ws;
  uint32* wq1   = (uint32*)(ws + 0);        // 98304
  uint32* wq2   = (uint32*)(ws + 98304);    // 98304
  uint32* wq3   = (uint32*)(ws + 196608);   // 98304
  uint32* wih1t = (uint32*)(ws + 294912);   // 12288
  uint32* wih2t = (uint32*)(ws + 307200);   // 1536
  uint32* wih3t = (uint32*)(ws + 308736);   // 1536
  float*  wz1t  = ws + 310272;              // 2304
  float*  wz2t  = ws + 312576;              // 2304
  uint32* wxp   = (uint32*)(ws + 314880);   // 8192
  float*  zx    = ws + 323072;              // 2097152  [L][B][8]
  uint32* zbuf  = (uint32*)(ws + 2420224);  // 524288   [L][B] f16x2 pairs

  float* out = (float*)d_out;  // [B*L*F] y_loc, then recon, kld
  hipMemsetAsync(out + 8388608, 0, 8, stream);

  prep_kernel<<<128, 256, 0, stream>>>(Wih1, Whh1, Wih2, Whh2, Wih3, Whh3,
                                       Wzl, Wzs, Wxl, Wxs,
                                       wq1, wq2, wq3, wih1t, wih2t, wih3t,
                                       wz1t, wz2t, wxp);
  enc_kernel<<<128, 512, 0, stream>>>(x, bih1, bhh1, wq1, wih1t, wz2t, zx);
  decA_kernel<<<128, 512, 0, stream>>>(eps, bih2, bhh2, wq2, wih2t, wz1t,
                                       bzl, bzs, zx, (uint16*)zbuf, out + 8388609);
  decB_kernel<<<128, 512, 0, stream>>>(x, bih3, bhh3, wq3, wih3t, wxp,
                                       bxl, bxs, zbuf, out, out + 8388608);
}